// Round 10
// baseline (226.464 us; speedup 1.0000x reference)
//
#include <hip/hip_runtime.h>
#include <hip/hip_bf16.h>

#define LL 512
#define BB 32
#define DD 256
#define NS 16
#define RK 16
#define CH 32          // chunks over L
#define LC 16          // L per chunk

typedef __attribute__((ext_vector_type(8))) short bf16x8;
typedef __attribute__((ext_vector_type(8))) _Float16 f16x8;
typedef __attribute__((ext_vector_type(4))) float f32x4;

// load 16 consecutive floats into a scalar array (float4 x4)
#define LD16(dst, src, off) { \
  float4 _v0 = *reinterpret_cast<const float4*>(&(src)[(off)]); \
  float4 _v1 = *reinterpret_cast<const float4*>(&(src)[(off)+4]); \
  float4 _v2 = *reinterpret_cast<const float4*>(&(src)[(off)+8]); \
  float4 _v3 = *reinterpret_cast<const float4*>(&(src)[(off)+12]); \
  dst[0]=_v0.x; dst[1]=_v0.y; dst[2]=_v0.z; dst[3]=_v0.w; \
  dst[4]=_v1.x; dst[5]=_v1.y; dst[6]=_v1.z; dst[7]=_v1.w; \
  dst[8]=_v2.x; dst[9]=_v2.y; dst[10]=_v2.z; dst[11]=_v2.w; \
  dst[12]=_v3.x; dst[13]=_v3.y; dst[14]=_v3.z; dst[15]=_v3.w; }

static __device__ __forceinline__ unsigned short f2bf(float x) {
    __hip_bfloat16 h = __float2bfloat16(x);
    return *reinterpret_cast<unsigned short*>(&h);
}

static __device__ __forceinline__ f16x8 ld_cvt_f16(const float* p) {
    float4 lo = *reinterpret_cast<const float4*>(p);
    float4 hi = *reinterpret_cast<const float4*>(p + 4);
    f16x8 r;
    r[0] = (_Float16)lo.x; r[1] = (_Float16)lo.y; r[2] = (_Float16)lo.z; r[3] = (_Float16)lo.w;
    r[4] = (_Float16)hi.x; r[5] = (_Float16)hi.y; r[6] = (_Float16)hi.z; r[7] = (_Float16)hi.w;
    return r;
}

// ---------------- K0a: W -> bf16 ----------------
__global__ __launch_bounds__(256) void k0_wbf(
    const float* __restrict__ W, unsigned short* __restrict__ Wbf)
{
    int i = (blockIdx.x * 256 + threadIdx.x) * 4;
    float4 v = *reinterpret_cast<const float4*>(&W[i]);
    ushort4 o;
    o.x = f2bf(v.x); o.y = f2bf(v.y); o.z = f2bf(v.z); o.w = f2bf(v.w);
    *reinterpret_cast<ushort4*>(&Wbf[i]) = o;
}

// ---------------- K0b: a[d,n] = -exp(A_log)*log2(e) ----------------
__global__ __launch_bounds__(256) void k0_atab(
    const float* __restrict__ A_log, float* __restrict__ atab)
{
    int i = blockIdx.x * 256 + threadIdx.x;     // 4096
    atab[i] = -__expf(A_log[i]) * 1.44269504f;
}

// ---------------- K1: fused projections via MFMA ----------------
// block: 64 rows (4 waves x 16 rows), grid 256.
// MFMA1: xdbl = flow @ xw^T (N=48).  B/C written straight from fragments.
// MFMA2: delta = softplus(xdbl[:, :16] @ dtw^T + b), via LDS transpose + K-padded 16x16x32.
__global__ __launch_bounds__(256) void k1_fused(
    const float* __restrict__ flow,       // (L,B,D)
    const float* __restrict__ xw,         // (48,D)
    const float* __restrict__ dtw,        // (D,RK)
    const float* __restrict__ dtb,        // (D)
    float* __restrict__ delta,            // (B,L,D)
    float* __restrict__ Bm,               // (B,L,NS)
    float* __restrict__ Cm)               // (B,L,NS)
{
    __shared__ float sx16[4][16][17];     // [wave][Mrow][r] 4.3 KB
    int wave = threadIdx.x >> 6;
    int lane = threadIdx.x & 63;
    int rl = lane & 15, kb = lane >> 4;
    int rowbase = blockIdx.x * 64 + wave * 16;
    int arow = rowbase + rl;
    int b = arow >> 9, l = arow & 511;
    const float* abase = &flow[(l * BB + b) * DD];

    f32x4 acc[3] = {};
    #pragma unroll
    for (int ks = 0; ks < 8; ++ks) {
        int k0 = ks * 32 + kb * 8;
        f16x8 af = ld_cvt_f16(abase + k0);
        #pragma unroll
        for (int j = 0; j < 3; ++j) {
            f16x8 bfr = ld_cvt_f16(&xw[(j * 16 + rl) * DD + k0]);
            acc[j] = __builtin_amdgcn_mfma_f32_16x16x32_f16(af, bfr, acc[j], 0, 0, 0);
        }
    }
    // C/D layout: col = rl, row = kb*4 + reg
    #pragma unroll
    for (int reg = 0; reg < 4; ++reg) {
        int row = rowbase + kb * 4 + reg;
        Bm[(size_t)row * NS + rl] = acc[1][reg];
        Cm[(size_t)row * NS + rl] = acc[2][reg];
        sx16[wave][kb * 4 + reg][rl] = acc[0][reg];
    }
    __syncthreads();

    // MFMA2: A[Mrow][r] from sx16 (K=16 padded to 32: kb>=2 lanes contribute zero)
    f16x8 a2;
    if (kb < 2) {
        #pragma unroll
        for (int j = 0; j < 8; ++j)
            a2[j] = (_Float16)sx16[wave][rl][kb * 8 + j];
    } else {
        #pragma unroll
        for (int j = 0; j < 8; ++j) a2[j] = (_Float16)0.f;
    }

    #pragma unroll 4
    for (int m = 0; m < 16; ++m) {
        f16x8 b2;
        if (kb < 2) {
            float4 lo = *reinterpret_cast<const float4*>(&dtw[(m * 16 + rl) * RK + kb * 8]);
            float4 hi = *reinterpret_cast<const float4*>(&dtw[(m * 16 + rl) * RK + kb * 8 + 4]);
            b2[0] = (_Float16)lo.x; b2[1] = (_Float16)lo.y; b2[2] = (_Float16)lo.z; b2[3] = (_Float16)lo.w;
            b2[4] = (_Float16)hi.x; b2[5] = (_Float16)hi.y; b2[6] = (_Float16)hi.z; b2[7] = (_Float16)hi.w;
        } else {
            #pragma unroll
            for (int j = 0; j < 8; ++j) b2[j] = (_Float16)0.f;
        }
        f32x4 acc2 = {};
        acc2 = __builtin_amdgcn_mfma_f32_16x16x32_f16(a2, b2, acc2, 0, 0, 0);
        int d = m * 16 + rl;
        float bias = dtb[d];
        #pragma unroll
        for (int reg = 0; reg < 4; ++reg) {
            float s = acc2[reg] + bias;
            float sp = fmaxf(s, 0.f) + log1pf(__expf(-fabsf(s)));
            delta[(size_t)(rowbase + kb * 4 + reg) * DD + d] = sp;
        }
    }
}

// ---------------- K2A: single-pass chunk scan ----------------
// grid: b(32) x dt(16); block 512 = c(32) x dl(16).  No LDS, no barriers.
// Writes: y_part (incl u*D), S_local (in-place over delta), h_fin, s_fin.
__global__ __launch_bounds__(512) void k2A(
    const float* __restrict__ u_pos,    // (L,B,D)
    const float* __restrict__ atab,     // (D,NS)
    const float* __restrict__ Dp,       // (D)
    float* __restrict__ delta,          // (B,L,D) read delta, write S_local
    const float* __restrict__ Bm,       // (B,L,NS)
    const float* __restrict__ Cm,       // (B,L,NS)
    float* __restrict__ ypart,          // (B,L,D)
    float* __restrict__ hfin,           // (B,CH,D,NS)
    float* __restrict__ sfin)           // (B,CH,D)
{
    int tid = threadIdx.x;
    int b  = blockIdx.x >> 4;
    int dt = blockIdx.x & 15;
    int dl = tid & 15, c = tid >> 4;
    int d  = dt * 16 + dl;
    int l0 = c * LC;

    float a[NS];
    LD16(a, atab, d * NS);
    float Dd = Dp[d];

    float* dp = delta + ((size_t)b * LL + l0) * DD + d;
    const float* up = u_pos + ((size_t)l0 * BB + b) * DD + d;
    const float* Bp = Bm + ((size_t)b * LL + l0) * NS;
    const float* Cp = Cm + ((size_t)b * LL + l0) * NS;
    float* yp = ypart + ((size_t)b * LL + l0) * DD + d;

    float h[NS];
    #pragma unroll
    for (int n = 0; n < NS; ++n) h[n] = 0.f;
    float s = 0.f;

    for (int l = 0; l < LC; ++l) {
        float dlt = dp[l * DD];
        float uv  = up[l * BB * DD];
        float Bv[NS], Cv[NS];
        LD16(Bv, Bp, l * NS);
        LD16(Cv, Cp, l * NS);
        s += dlt;
        float du = dlt * uv;
        float acc = uv * Dd;
        #pragma unroll
        for (int n = 0; n < NS; ++n) {
            float dA = exp2f(dlt * a[n]);
            h[n] = fmaf(dA, h[n], du * Bv[n]);
            acc = fmaf(h[n], Cv[n], acc);
        }
        yp[l * DD] = acc;
        dp[l * DD] = s;                 // inclusive local cumsum of delta
    }

    size_t o = (((size_t)b * CH + c) * DD + d);
    sfin[o] = s;
    #pragma unroll
    for (int n = 0; n < NS; n += 4)
        *reinterpret_cast<float4*>(&hfin[o * NS + n]) =
            make_float4(h[n], h[n+1], h[n+2], h[n+3]);
}

// ---------------- K2B: global chunk combine ----------------
// thread (b,d,n): prefix over CH chunks; h_in written in place over hfin.
__global__ __launch_bounds__(256) void k2B(
    const float* __restrict__ h0,       // (B,D,NS)
    const float* __restrict__ atab,     // (D,NS)
    const float* __restrict__ sfin,     // (B,CH,D)
    float* __restrict__ hfin,           // in: local h; out: h_in per chunk
    float* __restrict__ h_out)          // (B,D,NS)
{
    int t = blockIdx.x * 256 + threadIdx.x;
    int n = t & 15, d = (t >> 4) & 255, b = t >> 12;
    float an = atab[d * NS + n];
    float s = h0[t];
    for (int c = 0; c < CH; ++c) {
        size_t o = ((size_t)b * CH + c) * DD + d;
        float sf = sfin[o];
        size_t oh = o * NS + n;
        float hp = hfin[oh];
        hfin[oh] = s;
        s = fmaf(exp2f(an * sf), s, hp);
    }
    h_out[t] = s;
}

// ---------------- K2C: parallel finalize ----------------
// grid (b,l) = 16384 blocks x 256 d-threads:
//   y = y_part + sum_n C[l,n] * exp2(a[d,n]*S_local[l,d]) * h_in[c(l),d,n]
__global__ __launch_bounds__(256) void k2C(
    const float* __restrict__ atab,     // (D,NS)
    const float* __restrict__ Slocal,   // (B,L,D) = delta buffer
    const float* __restrict__ Cm,       // (B,L,NS)
    const float* __restrict__ hfin,     // h_in per chunk (B,CH,D,NS)
    const float* __restrict__ ypart,    // (B,L,D)
    unsigned short* __restrict__ ybf)   // (B,L,D) bf16
{
    int d = threadIdx.x;
    int b = blockIdx.x >> 9;
    int l = blockIdx.x & 511;
    int c = l >> 4;                     // LC = 16

    float a[NS], hin[NS], Cv[NS];
    LD16(a, atab, d * NS);
    LD16(hin, hfin, (((size_t)b * CH + c) * DD + d) * NS);
    LD16(Cv, Cm, ((size_t)b * LL + l) * NS);

    size_t idx = ((size_t)b * LL + l) * DD + d;
    float sS = Slocal[idx];
    float acc = ypart[idx];
    #pragma unroll
    for (int n = 0; n < NS; ++n)
        acc = fmaf(exp2f(a[n] * sS), Cv[n] * hin[n], acc);
    ybf[idx] = f2bf(acc);
}

// ---------------- K3: output projection via bf16 MFMA ----------------
// Out(16384,256) = Y @ W^T.  Block 32x128 (grid 1024 = 4/CU), wave 16x64.
__global__ __launch_bounds__(256) void k3_mfma(
    const unsigned short* __restrict__ Ybf,   // (16384,256)
    const unsigned short* __restrict__ Wbf,   // (256,256)
    float* __restrict__ Out)
{
    int wave = threadIdx.x >> 6;
    int lane = threadIdx.x & 63;
    int row0 = (blockIdx.x >> 1) * 32 + (wave >> 1) * 16;
    int col0 = (blockIdx.x & 1) * 128 + (wave & 1) * 64;
    int rl = lane & 15, kb = lane >> 4;

    f32x4 acc[4] = {};
    bf16x8 af, bf[4], afn, bfn[4];

    af = *reinterpret_cast<const bf16x8*>(&Ybf[(size_t)(row0 + rl) * DD + kb * 8]);
    #pragma unroll
    for (int j = 0; j < 4; ++j)
        bf[j] = *reinterpret_cast<const bf16x8*>(&Wbf[(size_t)(col0 + j * 16 + rl) * DD + kb * 8]);

    #pragma unroll
    for (int ks = 0; ks < 8; ++ks) {
        int kn = (ks + 1) * 32 + kb * 8;
        if (ks < 7) {
            afn = *reinterpret_cast<const bf16x8*>(&Ybf[(size_t)(row0 + rl) * DD + kn]);
            #pragma unroll
            for (int j = 0; j < 4; ++j)
                bfn[j] = *reinterpret_cast<const bf16x8*>(&Wbf[(size_t)(col0 + j * 16 + rl) * DD + kn]);
        }
        #pragma unroll
        for (int j = 0; j < 4; ++j)
            acc[j] = __builtin_amdgcn_mfma_f32_16x16x32_bf16(af, bf[j], acc[j], 0, 0, 0);
        af = afn;
        #pragma unroll
        for (int j = 0; j < 4; ++j) bf[j] = bfn[j];
    }

    // C/D: col = lane&15, row = (lane>>4)*4 + reg
    #pragma unroll
    for (int j = 0; j < 4; ++j)
        #pragma unroll
        for (int reg = 0; reg < 4; ++reg)
            Out[(size_t)(row0 + kb * 4 + reg) * DD + col0 + j * 16 + rl] = acc[j][reg];
}

extern "C" void kernel_launch(void* const* d_in, const int* in_sizes, int n_in,
                              void* d_out, int out_size, void* d_ws, size_t ws_size,
                              hipStream_t stream) {
    const float* pos  = (const float*)d_in[0];   // (L,B,D)
    const float* flow = (const float*)d_in[1];   // (L,B,D)
    const float* h0   = (const float*)d_in[2];   // (B,D,NS)
    const float* xw   = (const float*)d_in[3];   // (48,D)
    const float* dtw  = (const float*)d_in[4];   // (D,16)
    const float* dtb  = (const float*)d_in[5];   // (D)
    const float* alog = (const float*)d_in[6];   // (D,NS)
    const float* dpar = (const float*)d_in[7];   // (D)
    const float* ow   = (const float*)d_in[8];   // (256,256)

    float* out = (float*)d_out;                  // out0: 4,194,304 then h_final: 131,072

    float* ws    = (float*)d_ws;
    float* delta = ws;                           //  4,194,304  (S_local after k2A)
    float* Bmw   = ws + 4194304;                 //    262,144
    float* Cmw   = ws + 4456448;                 //    262,144
    float* ypart = ws + 4718592;                 //  4,194,304
    float* hfin  = ws + 8912896;                 //  4,194,304  (B*CH*D*NS)
    float* sfin  = ws + 13107200;                //    262,144  (B*CH*D)
    float* atab  = ws + 13369344;                //      4,096
    unsigned short* ybf = (unsigned short*)(ws + 13373440);  // 4,194,304 bf16 (8 MB)
    unsigned short* wbf = (unsigned short*)(ws + 15470592);  // 65,536 bf16
    // total ws: ~62 MB

    float* h_out = out + 32 * 512 * 256;

    k0_wbf  <<<64,    256, 0, stream>>>(ow, wbf);
    k0_atab <<<16,    256, 0, stream>>>(alog, atab);
    k1_fused<<<256,   256, 0, stream>>>(flow, xw, dtw, dtb, delta, Bmw, Cmw);
    k2A     <<<512,   512, 0, stream>>>(pos, atab, dpar, delta, Bmw, Cmw, ypart, hfin, sfin);
    k2B     <<<512,   256, 0, stream>>>(h0, atab, sfin, hfin, h_out);
    k2C     <<<16384, 256, 0, stream>>>(atab, delta, Cmw, hfin, ypart, ybf);
    k3_mfma <<<1024,  256, 0, stream>>>(ybf, wbf, out);
}

// Round 11
// 214.866 us; speedup vs baseline: 1.0540x; 1.0540x over previous
//
#include <hip/hip_runtime.h>
#include <hip/hip_bf16.h>

#define LL 512
#define BB 32
#define DD 256
#define NS 16
#define RK 16
#define CH 32          // chunks over L
#define LC 16          // L per chunk

typedef __attribute__((ext_vector_type(8))) short bf16x8;
typedef __attribute__((ext_vector_type(8))) _Float16 f16x8;
typedef __attribute__((ext_vector_type(4))) float f32x4;

// load 16 consecutive floats into a scalar array (float4 x4)
#define LD16(dst, src, off) { \
  float4 _v0 = *reinterpret_cast<const float4*>(&(src)[(off)]); \
  float4 _v1 = *reinterpret_cast<const float4*>(&(src)[(off)+4]); \
  float4 _v2 = *reinterpret_cast<const float4*>(&(src)[(off)+8]); \
  float4 _v3 = *reinterpret_cast<const float4*>(&(src)[(off)+12]); \
  dst[0]=_v0.x; dst[1]=_v0.y; dst[2]=_v0.z; dst[3]=_v0.w; \
  dst[4]=_v1.x; dst[5]=_v1.y; dst[6]=_v1.z; dst[7]=_v1.w; \
  dst[8]=_v2.x; dst[9]=_v2.y; dst[10]=_v2.z; dst[11]=_v2.w; \
  dst[12]=_v3.x; dst[13]=_v3.y; dst[14]=_v3.z; dst[15]=_v3.w; }

#define CP16(dst, src) { _Pragma("unroll") for (int _i = 0; _i < 16; ++_i) dst[_i] = src[_i]; }

static __device__ __forceinline__ unsigned short f2bf(float x) {
    __hip_bfloat16 h = __float2bfloat16(x);
    return *reinterpret_cast<unsigned short*>(&h);
}

static __device__ __forceinline__ f16x8 ld_cvt_f16(const float* p) {
    float4 lo = *reinterpret_cast<const float4*>(p);
    float4 hi = *reinterpret_cast<const float4*>(p + 4);
    f16x8 r;
    r[0] = (_Float16)lo.x; r[1] = (_Float16)lo.y; r[2] = (_Float16)lo.z; r[3] = (_Float16)lo.w;
    r[4] = (_Float16)hi.x; r[5] = (_Float16)hi.y; r[6] = (_Float16)hi.z; r[7] = (_Float16)hi.w;
    return r;
}

// ---------------- K0a: W -> bf16 ----------------
__global__ __launch_bounds__(256) void k0_wbf(
    const float* __restrict__ W, unsigned short* __restrict__ Wbf)
{
    int i = (blockIdx.x * 256 + threadIdx.x) * 4;
    float4 v = *reinterpret_cast<const float4*>(&W[i]);
    ushort4 o;
    o.x = f2bf(v.x); o.y = f2bf(v.y); o.z = f2bf(v.z); o.w = f2bf(v.w);
    *reinterpret_cast<ushort4*>(&Wbf[i]) = o;
}

// ---------------- K0b: a tables (both layouts) ----------------
__global__ __launch_bounds__(256) void k0_atab(
    const float* __restrict__ A_log, float* __restrict__ atab, float* __restrict__ atabT)
{
    int i = blockIdx.x * 256 + threadIdx.x;     // 4096 = d*NS+n
    int d = i >> 4, n = i & 15;
    float v = -__expf(A_log[i]) * 1.44269504f;
    atab[i] = v;                                 // [d][n]
    atabT[n * DD + d] = v;                       // [n][d]
}

// ---------------- K1: fused projections via MFMA (unchanged, passed R10) ----------------
__global__ __launch_bounds__(256) void k1_fused(
    const float* __restrict__ flow,       // (L,B,D)
    const float* __restrict__ xw,         // (48,D)
    const float* __restrict__ dtw,        // (D,RK)
    const float* __restrict__ dtb,        // (D)
    float* __restrict__ delta,            // (B,L,D)
    float* __restrict__ Bm,               // (B,L,NS)
    float* __restrict__ Cm)               // (B,L,NS)
{
    __shared__ float sx16[4][16][17];
    int wave = threadIdx.x >> 6;
    int lane = threadIdx.x & 63;
    int rl = lane & 15, kb = lane >> 4;
    int rowbase = blockIdx.x * 64 + wave * 16;
    int arow = rowbase + rl;
    int b = arow >> 9, l = arow & 511;
    const float* abase = &flow[(l * BB + b) * DD];

    f32x4 acc[3] = {};
    #pragma unroll
    for (int ks = 0; ks < 8; ++ks) {
        int k0 = ks * 32 + kb * 8;
        f16x8 af = ld_cvt_f16(abase + k0);
        #pragma unroll
        for (int j = 0; j < 3; ++j) {
            f16x8 bfr = ld_cvt_f16(&xw[(j * 16 + rl) * DD + k0]);
            acc[j] = __builtin_amdgcn_mfma_f32_16x16x32_f16(af, bfr, acc[j], 0, 0, 0);
        }
    }
    #pragma unroll
    for (int reg = 0; reg < 4; ++reg) {
        int row = rowbase + kb * 4 + reg;
        Bm[(size_t)row * NS + rl] = acc[1][reg];
        Cm[(size_t)row * NS + rl] = acc[2][reg];
        sx16[wave][kb * 4 + reg][rl] = acc[0][reg];
    }
    __syncthreads();

    f16x8 a2;
    if (kb < 2) {
        #pragma unroll
        for (int j = 0; j < 8; ++j)
            a2[j] = (_Float16)sx16[wave][rl][kb * 8 + j];
    } else {
        #pragma unroll
        for (int j = 0; j < 8; ++j) a2[j] = (_Float16)0.f;
    }

    #pragma unroll 4
    for (int m = 0; m < 16; ++m) {
        f16x8 b2;
        if (kb < 2) {
            float4 lo = *reinterpret_cast<const float4*>(&dtw[(m * 16 + rl) * RK + kb * 8]);
            float4 hi = *reinterpret_cast<const float4*>(&dtw[(m * 16 + rl) * RK + kb * 8 + 4]);
            b2[0] = (_Float16)lo.x; b2[1] = (_Float16)lo.y; b2[2] = (_Float16)lo.z; b2[3] = (_Float16)lo.w;
            b2[4] = (_Float16)hi.x; b2[5] = (_Float16)hi.y; b2[6] = (_Float16)hi.z; b2[7] = (_Float16)hi.w;
        } else {
            #pragma unroll
            for (int j = 0; j < 8; ++j) b2[j] = (_Float16)0.f;
        }
        f32x4 acc2 = {};
        acc2 = __builtin_amdgcn_mfma_f32_16x16x32_f16(a2, b2, acc2, 0, 0, 0);
        int d = m * 16 + rl;
        float bias = dtb[d];
        #pragma unroll
        for (int reg = 0; reg < 4; ++reg) {
            float s = acc2[reg] + bias;
            float sp = fmaxf(s, 0.f) + log1pf(__expf(-fabsf(s)));
            delta[(size_t)(rowbase + kb * 4 + reg) * DD + d] = sp;
        }
    }
}

// ---------------- K2A: single-pass chunk scan, software-pipelined ----------------
// grid: b(32) x dt(16); block 512 = c(32) x dl(16).  No LDS.
// Writes: y_part (incl u*D), S_local (in-place over delta), hfin [b][c][n][d], sfin [b][c][d].
__global__ __launch_bounds__(512, 4) void k2A(
    const float* __restrict__ u_pos,    // (L,B,D)
    const float* __restrict__ atab,     // (D,NS)
    const float* __restrict__ Dp,       // (D)
    float* __restrict__ delta,          // (B,L,D) read delta, write S_local
    const float* __restrict__ Bm,       // (B,L,NS)
    const float* __restrict__ Cm,       // (B,L,NS)
    float* __restrict__ ypart,          // (B,L,D)
    float* __restrict__ hfin,           // (B,CH,NS,D)
    float* __restrict__ sfin)           // (B,CH,D)
{
    int tid = threadIdx.x;
    int b  = blockIdx.x >> 4;
    int dt = blockIdx.x & 15;
    int dl = tid & 15, c = tid >> 4;
    int d  = dt * 16 + dl;
    int l0 = c * LC;

    float a[NS];
    LD16(a, atab, d * NS);
    float Dd = Dp[d];

    float* dp = delta + ((size_t)b * LL + l0) * DD + d;
    const float* up = u_pos + ((size_t)l0 * BB + b) * DD + d;
    const float* Bp = Bm + ((size_t)b * LL + l0) * NS;
    const float* Cp = Cm + ((size_t)b * LL + l0) * NS;
    float* yp = ypart + ((size_t)b * LL + l0) * DD + d;

    float h[NS];
    #pragma unroll
    for (int n = 0; n < NS; ++n) h[n] = 0.f;
    float s = 0.f;

    // prologue
    float dlt = dp[0], uv = up[0];
    float Bv[NS], Cv[NS];
    LD16(Bv, Bp, 0);
    LD16(Cv, Cp, 0);

    for (int l = 0; l < LC; ++l) {
        int lp = (l + 1 < LC) ? l + 1 : l;
        float dlt_n = dp[lp * DD];
        float uv_n  = up[lp * BB * DD];
        float Bn[NS], Cn[NS];
        LD16(Bn, Bp, lp * NS);
        LD16(Cn, Cp, lp * NS);

        s += dlt;
        float du = dlt * uv;
        float acc = uv * Dd;
        #pragma unroll
        for (int n = 0; n < NS; ++n) {
            float dA = exp2f(dlt * a[n]);
            h[n] = fmaf(dA, h[n], du * Bv[n]);
            acc = fmaf(h[n], Cv[n], acc);
        }
        yp[l * DD] = acc;
        dp[l * DD] = s;                 // inclusive local cumsum of delta

        dlt = dlt_n; uv = uv_n;
        CP16(Bv, Bn); CP16(Cv, Cn);
    }

    sfin[((size_t)b * CH + c) * DD + d] = s;
    #pragma unroll
    for (int n = 0; n < NS; ++n)
        hfin[(((size_t)b * CH + c) * NS + n) * DD + d] = h[n];
}

// ---------------- K2B: global chunk combine (all streams d-coalesced) ----------------
// grid = (b,n) = 512 blocks; thread = d.  h_in written in place over hfin.
__global__ __launch_bounds__(256) void k2B(
    const float* __restrict__ h0,       // (B,D,NS)
    const float* __restrict__ atabT,    // (NS,D)
    const float* __restrict__ sfin,     // (B,CH,D)
    float* __restrict__ hfin,           // (B,CH,NS,D): in local h, out h_in
    float* __restrict__ h_out)          // (B,D,NS)
{
    int d = threadIdx.x;
    int b = blockIdx.x >> 4;
    int n = blockIdx.x & 15;
    float an = atabT[n * DD + d];
    float s = h0[((size_t)b * DD + d) * NS + n];
    #pragma unroll 4
    for (int c = 0; c < CH; ++c) {
        float sf = sfin[((size_t)b * CH + c) * DD + d];
        size_t oh = (((size_t)b * CH + c) * NS + n) * DD + d;
        float hp = hfin[oh];
        hfin[oh] = s;
        s = fmaf(exp2f(an * sf), s, hp);
    }
    h_out[((size_t)b * DD + d) * NS + n] = s;
}

// ---------------- K2C: parallel finalize, one block per (b,chunk) ----------------
// y = y_part + sum_n C[l,n] * exp2(a[d,n]*S_local[l,d]) * h_in[c,d,n]
__global__ __launch_bounds__(256) void k2C(
    const float* __restrict__ atabT,    // (NS,D)
    const float* __restrict__ Slocal,   // (B,L,D) = delta buffer
    const float* __restrict__ Cm,       // (B,L,NS)
    const float* __restrict__ hfin,     // (B,CH,NS,D) h_in
    const float* __restrict__ ypart,    // (B,L,D)
    unsigned short* __restrict__ ybf)   // (B,L,D) bf16
{
    int d = threadIdx.x;
    int b = blockIdx.x >> 5;
    int c = blockIdx.x & 31;
    int l0 = c * LC;

    float a[NS], hin[NS];
    #pragma unroll
    for (int n = 0; n < NS; ++n) {
        a[n]   = atabT[n * DD + d];
        hin[n] = hfin[(((size_t)b * CH + c) * NS + n) * DD + d];
    }

    size_t base = ((size_t)b * LL + l0) * DD + d;
    const float* CpB = Cm + ((size_t)b * LL + l0) * NS;

    #pragma unroll 2
    for (int l = 0; l < LC; ++l) {
        float Cv[NS];
        LD16(Cv, CpB, l * NS);          // wave-uniform broadcast
        size_t idx = base + (size_t)l * DD;
        float sS = Slocal[idx];
        float acc = ypart[idx];
        #pragma unroll
        for (int n = 0; n < NS; ++n)
            acc = fmaf(exp2f(a[n] * sS), Cv[n] * hin[n], acc);
        ybf[idx] = f2bf(acc);
    }
}

// ---------------- K3: output projection via bf16 MFMA (unchanged) ----------------
__global__ __launch_bounds__(256) void k3_mfma(
    const unsigned short* __restrict__ Ybf,   // (16384,256)
    const unsigned short* __restrict__ Wbf,   // (256,256)
    float* __restrict__ Out)
{
    int wave = threadIdx.x >> 6;
    int lane = threadIdx.x & 63;
    int row0 = (blockIdx.x >> 1) * 32 + (wave >> 1) * 16;
    int col0 = (blockIdx.x & 1) * 128 + (wave & 1) * 64;
    int rl = lane & 15, kb = lane >> 4;

    f32x4 acc[4] = {};
    bf16x8 af, bf[4], afn, bfn[4];

    af = *reinterpret_cast<const bf16x8*>(&Ybf[(size_t)(row0 + rl) * DD + kb * 8]);
    #pragma unroll
    for (int j = 0; j < 4; ++j)
        bf[j] = *reinterpret_cast<const bf16x8*>(&Wbf[(size_t)(col0 + j * 16 + rl) * DD + kb * 8]);

    #pragma unroll
    for (int ks = 0; ks < 8; ++ks) {
        int kn = (ks + 1) * 32 + kb * 8;
        if (ks < 7) {
            afn = *reinterpret_cast<const bf16x8*>(&Ybf[(size_t)(row0 + rl) * DD + kn]);
            #pragma unroll
            for (int j = 0; j < 4; ++j)
                bfn[j] = *reinterpret_cast<const bf16x8*>(&Wbf[(size_t)(col0 + j * 16 + rl) * DD + kn]);
        }
        #pragma unroll
        for (int j = 0; j < 4; ++j)
            acc[j] = __builtin_amdgcn_mfma_f32_16x16x32_bf16(af, bf[j], acc[j], 0, 0, 0);
        af = afn;
        #pragma unroll
        for (int j = 0; j < 4; ++j) bf[j] = bfn[j];
    }

    #pragma unroll
    for (int j = 0; j < 4; ++j)
        #pragma unroll
        for (int reg = 0; reg < 4; ++reg)
            Out[(size_t)(row0 + kb * 4 + reg) * DD + col0 + j * 16 + rl] = acc[j][reg];
}

extern "C" void kernel_launch(void* const* d_in, const int* in_sizes, int n_in,
                              void* d_out, int out_size, void* d_ws, size_t ws_size,
                              hipStream_t stream) {
    const float* pos  = (const float*)d_in[0];   // (L,B,D)
    const float* flow = (const float*)d_in[1];   // (L,B,D)
    const float* h0   = (const float*)d_in[2];   // (B,D,NS)
    const float* xw   = (const float*)d_in[3];   // (48,D)
    const float* dtw  = (const float*)d_in[4];   // (D,16)
    const float* dtb  = (const float*)d_in[5];   // (D)
    const float* alog = (const float*)d_in[6];   // (D,NS)
    const float* dpar = (const float*)d_in[7];   // (D)
    const float* ow   = (const float*)d_in[8];   // (256,256)

    float* out = (float*)d_out;                  // out0: 4,194,304 then h_final: 131,072

    float* ws    = (float*)d_ws;
    float* delta = ws;                           //  4,194,304  (S_local after k2A)
    float* Bmw   = ws + 4194304;                 //    262,144
    float* Cmw   = ws + 4456448;                 //    262,144
    float* ypart = ws + 4718592;                 //  4,194,304
    float* hfin  = ws + 8912896;                 //  4,194,304  (B,CH,NS,D)
    float* sfin  = ws + 13107200;                //    262,144  (B,CH,D)
    float* atab  = ws + 13369344;                //      4,096  (D,NS)
    float* atabT = ws + 13373440;                //      4,096  (NS,D)
    unsigned short* ybf = (unsigned short*)(ws + 13377536);  // 4,194,304 bf16
    unsigned short* wbf = (unsigned short*)(ws + 15474688);  // 65,536 bf16
    // total ws: ~62 MB (same footprint as R10, which ran)

    float* h_out = out + 32 * 512 * 256;

    k0_wbf  <<<64,   256, 0, stream>>>(ow, wbf);
    k0_atab <<<16,   256, 0, stream>>>(alog, atab, atabT);
    k1_fused<<<256,  256, 0, stream>>>(flow, xw, dtw, dtb, delta, Bmw, Cmw);
    k2A     <<<512,  512, 0, stream>>>(pos, atab, dpar, delta, Bmw, Cmw, ypart, hfin, sfin);
    k2B     <<<512,  256, 0, stream>>>(h0, atabT, sfin, hfin, h_out);
    k2C     <<<1024, 256, 0, stream>>>(atabT, delta, Cmw, hfin, ypart, ybf);
    k3_mfma <<<1024, 256, 0, stream>>>(ybf, wbf, out);
}

// Round 12
// 214.297 us; speedup vs baseline: 1.0568x; 1.0027x over previous
//
#include <hip/hip_runtime.h>
#include <hip/hip_bf16.h>

#define LL 512
#define BB 32
#define DD 256
#define NS 16
#define RK 16
#define CH 32          // chunks over L
#define LC 16          // L per chunk
#define L2E 1.44269504f

typedef __attribute__((ext_vector_type(8))) _Float16 f16x8;
typedef __attribute__((ext_vector_type(4))) float f32x4;

// load 16 consecutive floats into a scalar array (float4 x4)
#define LD16(dst, src, off) { \
  float4 _v0 = *reinterpret_cast<const float4*>(&(src)[(off)]); \
  float4 _v1 = *reinterpret_cast<const float4*>(&(src)[(off)+4]); \
  float4 _v2 = *reinterpret_cast<const float4*>(&(src)[(off)+8]); \
  float4 _v3 = *reinterpret_cast<const float4*>(&(src)[(off)+12]); \
  dst[0]=_v0.x; dst[1]=_v0.y; dst[2]=_v0.z; dst[3]=_v0.w; \
  dst[4]=_v1.x; dst[5]=_v1.y; dst[6]=_v1.z; dst[7]=_v1.w; \
  dst[8]=_v2.x; dst[9]=_v2.y; dst[10]=_v2.z; dst[11]=_v2.w; \
  dst[12]=_v3.x; dst[13]=_v3.y; dst[14]=_v3.z; dst[15]=_v3.w; }

// load 8 consecutive floats
#define LD8(dst, src, off) { \
  float4 _v0 = *reinterpret_cast<const float4*>(&(src)[(off)]); \
  float4 _v1 = *reinterpret_cast<const float4*>(&(src)[(off)+4]); \
  dst[0]=_v0.x; dst[1]=_v0.y; dst[2]=_v0.z; dst[3]=_v0.w; \
  dst[4]=_v1.x; dst[5]=_v1.y; dst[6]=_v1.z; dst[7]=_v1.w; }

static __device__ __forceinline__ f16x8 ld_cvt_f16(const float* p) {
    float4 lo = *reinterpret_cast<const float4*>(p);
    float4 hi = *reinterpret_cast<const float4*>(p + 4);
    f16x8 r;
    r[0] = (_Float16)lo.x; r[1] = (_Float16)lo.y; r[2] = (_Float16)lo.z; r[3] = (_Float16)lo.w;
    r[4] = (_Float16)hi.x; r[5] = (_Float16)hi.y; r[6] = (_Float16)hi.z; r[7] = (_Float16)hi.w;
    return r;
}

// ---------------- K1: fused projections via MFMA (unchanged, passed R10/R11) ----------------
__global__ __launch_bounds__(256) void k1_fused(
    const float* __restrict__ flow,       // (L,B,D)
    const float* __restrict__ xw,         // (48,D)
    const float* __restrict__ dtw,        // (D,RK)
    const float* __restrict__ dtb,        // (D)
    float* __restrict__ delta,            // (B,L,D)
    float* __restrict__ Bm,               // (B,L,NS)
    float* __restrict__ Cm)               // (B,L,NS)
{
    __shared__ float sx16[4][16][17];
    int wave = threadIdx.x >> 6;
    int lane = threadIdx.x & 63;
    int rl = lane & 15, kb = lane >> 4;
    int rowbase = blockIdx.x * 64 + wave * 16;
    int arow = rowbase + rl;
    int b = arow >> 9, l = arow & 511;
    const float* abase = &flow[(l * BB + b) * DD];

    f32x4 acc[3] = {};
    #pragma unroll
    for (int ks = 0; ks < 8; ++ks) {
        int k0 = ks * 32 + kb * 8;
        f16x8 af = ld_cvt_f16(abase + k0);
        #pragma unroll
        for (int j = 0; j < 3; ++j) {
            f16x8 bfr = ld_cvt_f16(&xw[(j * 16 + rl) * DD + k0]);
            acc[j] = __builtin_amdgcn_mfma_f32_16x16x32_f16(af, bfr, acc[j], 0, 0, 0);
        }
    }
    #pragma unroll
    for (int reg = 0; reg < 4; ++reg) {
        int row = rowbase + kb * 4 + reg;
        Bm[(size_t)row * NS + rl] = acc[1][reg];
        Cm[(size_t)row * NS + rl] = acc[2][reg];
        sx16[wave][kb * 4 + reg][rl] = acc[0][reg];
    }
    __syncthreads();

    f16x8 a2;
    if (kb < 2) {
        #pragma unroll
        for (int j = 0; j < 8; ++j)
            a2[j] = (_Float16)sx16[wave][rl][kb * 8 + j];
    } else {
        #pragma unroll
        for (int j = 0; j < 8; ++j) a2[j] = (_Float16)0.f;
    }

    #pragma unroll 4
    for (int m = 0; m < 16; ++m) {
        f16x8 b2;
        if (kb < 2) {
            float4 lo = *reinterpret_cast<const float4*>(&dtw[(m * 16 + rl) * RK + kb * 8]);
            float4 hi = *reinterpret_cast<const float4*>(&dtw[(m * 16 + rl) * RK + kb * 8 + 4]);
            b2[0] = (_Float16)lo.x; b2[1] = (_Float16)lo.y; b2[2] = (_Float16)lo.z; b2[3] = (_Float16)lo.w;
            b2[4] = (_Float16)hi.x; b2[5] = (_Float16)hi.y; b2[6] = (_Float16)hi.z; b2[7] = (_Float16)hi.w;
        } else {
            #pragma unroll
            for (int j = 0; j < 8; ++j) b2[j] = (_Float16)0.f;
        }
        f32x4 acc2 = {};
        acc2 = __builtin_amdgcn_mfma_f32_16x16x32_f16(a2, b2, acc2, 0, 0, 0);
        int d = m * 16 + rl;
        float bias = dtb[d];
        #pragma unroll
        for (int reg = 0; reg < 4; ++reg) {
            float s = acc2[reg] + bias;
            float sp = fmaxf(s, 0.f) + log1pf(__expf(-fabsf(s)));
            delta[(size_t)(rowbase + kb * 4 + reg) * DD + d] = sp;
        }
    }
}

// ---------------- K2A: single-pass chunk scan, n-split for occupancy ----------------
// grid 1024 = b(32) x dt(16) x cg(2); block 512 = cl(16) x nh(2) x dl(16).
// Thread handles 8 of the 16 states; y via shfl_xor(16).  No LDS.
__global__ __launch_bounds__(512, 4) void k2A(
    const float* __restrict__ u_pos,    // (L,B,D)
    const float* __restrict__ A_log,    // (D,NS)
    const float* __restrict__ Dp,       // (D)
    float* __restrict__ delta,          // (B,L,D) read delta, write S_local
    const float* __restrict__ Bm,       // (B,L,NS)
    const float* __restrict__ Cm,       // (B,L,NS)
    float* __restrict__ ypart,          // (B,L,D)  y incl u*D
    float* __restrict__ hfin,           // (B,CH,NS,D)
    float* __restrict__ sfin)           // (B,CH,D)
{
    int tid = threadIdx.x;
    int bid = blockIdx.x;
    int cg = bid & 1;
    int dt = (bid >> 1) & 15;
    int b  = bid >> 5;
    int dl = tid & 15;
    int nh = (tid >> 4) & 1;
    int cl = tid >> 5;                  // 0..15
    int c  = cg * 16 + cl;
    int d  = dt * 16 + dl;
    int l0 = c * LC;

    float a[8];
    LD8(a, A_log, d * NS + nh * 8);
    #pragma unroll
    for (int n = 0; n < 8; ++n) a[n] = -__expf(a[n]) * L2E;
    float Dd = Dp[d];

    float* dp = delta + ((size_t)b * LL + l0) * DD + d;
    const float* up = u_pos + ((size_t)l0 * BB + b) * DD + d;
    const float* Bp = Bm + ((size_t)b * LL + l0) * NS + nh * 8;
    const float* Cp = Cm + ((size_t)b * LL + l0) * NS + nh * 8;
    float* yp = ypart + ((size_t)b * LL + l0) * DD + d;

    float h[8];
    #pragma unroll
    for (int n = 0; n < 8; ++n) h[n] = 0.f;
    float s = 0.f;

    for (int l = 0; l < LC; ++l) {
        float dlt = dp[l * DD];
        float uv  = up[l * BB * DD];
        float Bv[8], Cv[8];
        LD8(Bv, Bp, l * NS);
        LD8(Cv, Cp, l * NS);
        s += dlt;
        float du = dlt * uv;
        float acc = nh ? 0.f : uv * Dd;
        #pragma unroll
        for (int n = 0; n < 8; ++n) {
            float dA = exp2f(dlt * a[n]);
            h[n] = fmaf(dA, h[n], du * Bv[n]);
            acc = fmaf(h[n], Cv[n], acc);
        }
        acc += __shfl_xor(acc, 16);     // combine the two n-halves (same d, c)
        if (!nh) {
            yp[l * DD] = acc;
            dp[l * DD] = s;             // inclusive local cumsum of delta
        }
    }

    if (!nh) sfin[((size_t)b * CH + c) * DD + d] = s;
    #pragma unroll
    for (int n = 0; n < 8; ++n)
        hfin[(((size_t)b * CH + c) * NS + nh * 8 + n) * DD + d] = h[n];
}

// ---------------- K2B: global chunk combine (d-coalesced) ----------------
// grid = (b,n) = 512 blocks; thread = d.  h_in written in place over hfin.
__global__ __launch_bounds__(256) void k2B(
    const float* __restrict__ h0,       // (B,D,NS)
    const float* __restrict__ A_log,    // (D,NS)
    const float* __restrict__ sfin,     // (B,CH,D)
    float* __restrict__ hfin,           // (B,CH,NS,D): in local h, out h_in
    float* __restrict__ h_out)          // (B,D,NS)
{
    int d = threadIdx.x;
    int b = blockIdx.x >> 4;
    int n = blockIdx.x & 15;
    float an = -__expf(A_log[d * NS + n]) * L2E;
    float s = h0[((size_t)b * DD + d) * NS + n];
    #pragma unroll 4
    for (int c = 0; c < CH; ++c) {
        float sf = sfin[((size_t)b * CH + c) * DD + d];
        size_t oh = (((size_t)b * CH + c) * NS + n) * DD + d;
        float hp = hfin[oh];
        hfin[oh] = s;
        s = fmaf(exp2f(an * sf), s, hp);
    }
    h_out[((size_t)b * DD + d) * NS + n] = s;
}

// ---------------- K23: finalize y into LDS (f16) + output GEMM ----------------
// grid 512 = b(32) x rowgroup(16, 32 rows each); block 512.
// Phase 1: y = y_part + sum_n C*exp2(a*S)*h_in  ->  sy (f16, padded).
// Phase 2: Out[32 x 256] = sy @ W^T via f16 MFMA (W converted inline; L2-resident).
__global__ __launch_bounds__(512) void k23(
    const float* __restrict__ A_log,    // (D,NS)
    const float* __restrict__ Slocal,   // (B,L,D) = delta buffer
    const float* __restrict__ Cm,       // (B,L,NS)
    const float* __restrict__ hfin,     // (B,CH,NS,D) h_in
    const float* __restrict__ ypart,    // (B,L,D)
    const float* __restrict__ W,        // (256,256) fp32
    float* __restrict__ Out)            // (B,L,D_MODEL)
{
    __shared__ _Float16 sy[32][264];    // pad 8 f16 -> row stride 528 B (2-way banks)
    int tid = threadIdx.x;
    int b  = blockIdx.x >> 4;
    int rg = blockIdx.x & 15;
    int l0 = rg * 32;

    // ---- phase 1: 512 threads = lgrp(2) x d(256); 16 l's each ----
    {
        int d = tid & 255, lgrp = tid >> 8;
        int c = rg * 2 + lgrp;
        float a[NS], hin[NS];
        LD16(a, A_log, d * NS);
        #pragma unroll
        for (int n = 0; n < NS; ++n) {
            a[n] = -__expf(a[n]) * L2E;
            hin[n] = hfin[(((size_t)b * CH + c) * NS + n) * DD + d];
        }
        size_t base = ((size_t)b * LL + l0 + lgrp * 16) * DD + d;
        const float* Cp = Cm + ((size_t)b * LL + l0 + lgrp * 16) * NS;
        #pragma unroll 2
        for (int i = 0; i < 16; ++i) {
            float Cv[NS];
            LD16(Cv, Cp, i * NS);       // wave-uniform broadcast
            size_t idx = base + (size_t)i * DD;
            float sS = Slocal[idx];
            float acc = ypart[idx];
            #pragma unroll
            for (int n = 0; n < NS; ++n)
                acc = fmaf(exp2f(a[n] * sS), Cv[n] * hin[n], acc);
            sy[lgrp * 16 + i][d] = (_Float16)acc;
        }
    }
    __syncthreads();

    // ---- phase 2: 8 waves = rowg(2) x colg(4); wave tile 16 x 64 ----
    {
        int wave = tid >> 6, lane = tid & 63;
        int rl = lane & 15, kb = lane >> 4;
        int rowg = wave & 1, colg = wave >> 1;
        f32x4 acc[4] = {};
        #pragma unroll
        for (int ks = 0; ks < 8; ++ks) {
            int k0 = ks * 32 + kb * 8;
            f16x8 af = *reinterpret_cast<const f16x8*>(&sy[rowg * 16 + rl][k0]);
            #pragma unroll
            for (int j = 0; j < 4; ++j) {
                f16x8 bfr = ld_cvt_f16(&W[(colg * 64 + j * 16 + rl) * DD + k0]);
                acc[j] = __builtin_amdgcn_mfma_f32_16x16x32_f16(af, bfr, acc[j], 0, 0, 0);
            }
        }
        // C/D: col = rl, row = kb*4 + reg
        size_t grow = (size_t)b * LL + l0 + rowg * 16 + kb * 4;
        #pragma unroll
        for (int j = 0; j < 4; ++j)
            #pragma unroll
            for (int reg = 0; reg < 4; ++reg)
                Out[(grow + reg) * DD + colg * 64 + j * 16 + rl] = acc[j][reg];
    }
}

extern "C" void kernel_launch(void* const* d_in, const int* in_sizes, int n_in,
                              void* d_out, int out_size, void* d_ws, size_t ws_size,
                              hipStream_t stream) {
    const float* pos  = (const float*)d_in[0];   // (L,B,D)
    const float* flow = (const float*)d_in[1];   // (L,B,D)
    const float* h0   = (const float*)d_in[2];   // (B,D,NS)
    const float* xw   = (const float*)d_in[3];   // (48,D)
    const float* dtw  = (const float*)d_in[4];   // (D,16)
    const float* dtb  = (const float*)d_in[5];   // (D)
    const float* alog = (const float*)d_in[6];   // (D,NS)
    const float* dpar = (const float*)d_in[7];   // (D)
    const float* ow   = (const float*)d_in[8];   // (256,256)

    float* out = (float*)d_out;                  // out0: 4,194,304 then h_final: 131,072

    float* ws    = (float*)d_ws;
    float* delta = ws;                           //  4,194,304  (S_local after k2A)
    float* Bmw   = ws + 4194304;                 //    262,144
    float* Cmw   = ws + 4456448;                 //    262,144
    float* ypart = ws + 4718592;                 //  4,194,304
    float* hfin  = ws + 8912896;                 //  4,194,304  (B,CH,NS,D)
    float* sfin  = ws + 13107200;                //    262,144  (B,CH,D)
    // total ws: ~53.5 MB

    float* h_out = out + 32 * 512 * 256;

    k1_fused<<<256,  256, 0, stream>>>(flow, xw, dtw, dtb, delta, Bmw, Cmw);
    k2A     <<<1024, 512, 0, stream>>>(pos, alog, dpar, delta, Bmw, Cmw, ypart, hfin, sfin);
    k2B     <<<512,  256, 0, stream>>>(h0, alog, sfin, hfin, h_out);
    k23     <<<512,  512, 0, stream>>>(alog, delta, Cmw, hfin, ypart, ow, out);
}